// Round 2
// 331.726 us; speedup vs baseline: 1.0457x; 1.0457x over previous
//
#include <hip/hip_runtime.h>
#include <cstdint>

// Problem constants
#define U_UNITS 64
#define M_SLOTS 8192
#define D_DIM   64
#define SCH     16                // softmax split-K chunks per unit
#define CHUNK   (M_SLOTS / SCH)   // 512 slots per chunk
#define BLK     256

// ---------------------------------------------------------------------------
// Kernel A (fused): per (unit, chunk) block of 512 slots:
//   phase 1: scores = (attentions · attention), masked, /tmpr -> LDS only
//            (no global staging roundtrip), block-local max.
//   phase 2: we = exp(score - lmax); write UNNORMALIZED weights to the
//            weights output region; accumulate unnormalized PV partial;
//            stream memories -> out_m copy (memories read exactly once).
//   emit pmax[b] = lmax, psum[b] = sum(we), pout[b][:] = PV partial.
// Final normalization happens via alpha_c = exp(lmax_c - gmax)/gsum:
//   weights = we * alpha   (wfix_kernel, 4 MB traffic)
//   outputs = sum_c alpha_c * pout_c   (combine_out_kernel)
// grid = U*SCH = 1024 blocks, 256 threads (8 waves). 16 lanes per slot,
// each lane covers 4 consecutive f32 (float4); a wave reads 1 KiB contiguous.
// ---------------------------------------------------------------------------
__global__ __launch_bounds__(BLK) void fused_kernel(
    const float* __restrict__ att,    // [U][D]
    const float* __restrict__ atts,   // [U][M][D]
    const float* __restrict__ tmpr,   // [U]
    const int*   __restrict__ mask,   // [U][M] (nonzero -> dropped)
    const float* __restrict__ mem,    // [U][M][D]
    float* __restrict__ out_w,        // [U][M]  (unnormalized until wfix)
    float* __restrict__ out_m,        // [U][M][D] pass-through copy
    float* __restrict__ pmax,         // [U*SCH]
    float* __restrict__ psum,         // [U*SCH]
    float* __restrict__ pout)         // [U*SCH][D] unnormalized PV partials
{
    const int b = blockIdx.x;
    const int u = b / SCH, c = b % SCH;
    const int tid = threadIdx.x;

    __shared__ float s_att[D_DIM];
    __shared__ float s_w[CHUNK];
    __shared__ float s_m[4], s_s[4];
    __shared__ float s_acc[4 * D_DIM];

    if (tid < D_DIM) s_att[tid] = att[u * D_DIM + tid];
    __syncthreads();

    const int cg = (tid & 15) * 4;        // column-group start (4 floats)
    const float a0 = s_att[cg], a1 = s_att[cg + 1];
    const float a2 = s_att[cg + 2], a3 = s_att[cg + 3];
    const float invt = 1.0f / tmpr[u];

    const size_t ubase = (size_t)u * M_SLOTS * D_DIM + (size_t)c * CHUNK * D_DIM;
    const float* __restrict__ abase = atts + ubase;

    // ---- phase 1: scores -> LDS, running max ----
    float lmx = -1e30f;
    #pragma unroll 4
    for (int k = 0; k < CHUNK / 16; ++k) {          // 32 iterations, 16 slots each
        const int sl = k * 16 + (tid >> 4);
        const float4 v = *(const float4*)(abase + (size_t)sl * D_DIM + cg);
        float d = v.x * a0 + v.y * a1 + v.z * a2 + v.w * a3;
        d += __shfl_xor(d, 1);
        d += __shfl_xor(d, 2);
        d += __shfl_xor(d, 4);
        d += __shfl_xor(d, 8);
        const float wv = mask[u * M_SLOTS + c * CHUNK + sl] ? -1e30f : d * invt;
        lmx = fmaxf(lmx, wv);
        if ((tid & 15) == 0) s_w[sl] = wv;
    }
    #pragma unroll
    for (int off = 1; off < 64; off <<= 1) lmx = fmaxf(lmx, __shfl_xor(lmx, off));
    if ((tid & 63) == 0) s_m[tid >> 6] = lmx;
    __syncthreads();                      // also publishes s_w
    const float mx = fmaxf(fmaxf(s_m[0], s_m[1]), fmaxf(s_m[2], s_m[3]));

    // ---- phase 2: exp once; weights out, PV accumulate, memories copy ----
    const float* __restrict__ mbase = mem + ubase;
    float* __restrict__ obase = out_m + ubase;
    float acc0 = 0.f, acc1 = 0.f, acc2 = 0.f, acc3 = 0.f;
    float sm = 0.f;                       // each slot counted 16x (broadcast), /16 later
    #pragma unroll 4
    for (int k = 0; k < CHUNK / 16; ++k) {
        const int sl = k * 16 + (tid >> 4);
        const float we = __expf(s_w[sl] - mx);      // LDS broadcast read
        const float4 v = *(const float4*)(mbase + (size_t)sl * D_DIM + cg);
        *(float4*)(obase + (size_t)sl * D_DIM + cg) = v;   // pass-through copy
        acc0 += we * v.x;
        acc1 += we * v.y;
        acc2 += we * v.z;
        acc3 += we * v.w;
        sm += we;
        if ((tid & 15) == 0)
            out_w[(size_t)u * M_SLOTS + c * CHUNK + sl] = we;  // unnormalized
    }

    // reduce PV across the 4 slot-subgroups within each wave (xor bits 4,5)
    float acc[4] = {acc0, acc1, acc2, acc3};
    #pragma unroll
    for (int j = 0; j < 4; ++j) {
        acc[j] += __shfl_xor(acc[j], 16);
        acc[j] += __shfl_xor(acc[j], 32);
    }
    // wave-reduce the exp-sum (64 lanes = 16x over-count)
    #pragma unroll
    for (int off = 1; off < 64; off <<= 1) sm += __shfl_xor(sm, off);

    const int lane = tid & 63, w = tid >> 6;
    if (lane == 0) s_s[w] = sm;
    if (lane < 16) {
        #pragma unroll
        for (int j = 0; j < 4; ++j) s_acc[w * D_DIM + lane * 4 + j] = acc[j];
    }
    __syncthreads();
    if (tid < D_DIM) {
        const float s = s_acc[tid] + s_acc[D_DIM + tid]
                      + s_acc[2 * D_DIM + tid] + s_acc[3 * D_DIM + tid];
        pout[(size_t)b * D_DIM + tid] = s;
    }
    if (tid == 0) {
        pmax[b] = mx;
        psum[b] = (s_s[0] + s_s[1] + s_s[2] + s_s[3]) * 0.0625f;  // /16, exact pow2
    }
}

// ---------------------------------------------------------------------------
// Kernel B: per-unit global stats + final outputs + per-chunk alpha.
// grid = U blocks x D threads. Folds the old out_kernel in.
// ---------------------------------------------------------------------------
__global__ void combine_out_kernel(
    const float* __restrict__ pmax,
    const float* __restrict__ psum,
    const float* __restrict__ pout,
    float* __restrict__ alpha,        // [U*SCH]
    float* __restrict__ out_o)        // [U][D]
{
    const int u = blockIdx.x, t = threadIdx.x;
    float mx = -1e30f;
    #pragma unroll
    for (int c = 0; c < SCH; ++c) mx = fmaxf(mx, pmax[u * SCH + c]);
    float s = 0.f;
    #pragma unroll
    for (int c = 0; c < SCH; ++c) s += psum[u * SCH + c] * __expf(pmax[u * SCH + c] - mx);
    const float inv = 1.0f / s;
    float o = 0.f;
    #pragma unroll
    for (int c = 0; c < SCH; ++c)
        o += __expf(pmax[u * SCH + c] - mx) * inv * pout[((size_t)u * SCH + c) * D_DIM + t];
    out_o[u * D_DIM + t] = o;
    if (t < SCH) alpha[u * SCH + t] = __expf(pmax[u * SCH + t] - mx) * inv;
}

// ---------------------------------------------------------------------------
// Kernel C: weights fixup in place: out_w *= alpha[u, chunk].  4 MB traffic.
// One float4 per thread; chunk boundary (512) is float4-aligned so alpha is
// uniform within a float4. grid = U*M/4/BLK = 512 blocks.
// ---------------------------------------------------------------------------
__global__ __launch_bounds__(BLK) void wfix_kernel(
    const float* __restrict__ alpha,
    float* __restrict__ out_w)
{
    const int g = blockIdx.x * BLK + threadIdx.x;   // float4 index, U*M/4 total
    const int u = g >> 11;                          // 2048 float4 per unit
    const int c = (g & 2047) >> 7;                  // 128 float4 per chunk
    const float a = alpha[u * SCH + c];
    float4* p = reinterpret_cast<float4*>(out_w) + g;
    float4 v = *p;
    v.x *= a; v.y *= a; v.z *= a; v.w *= a;
    *p = v;
}

extern "C" void kernel_launch(void* const* d_in, const int* in_sizes, int n_in,
                              void* d_out, int out_size, void* d_ws, size_t ws_size,
                              hipStream_t stream)
{
    const float* att  = (const float*)d_in[0];  // attention  [64,64]
    const float* atts = (const float*)d_in[1];  // attentions [64,8192,64]
    const float* mem  = (const float*)d_in[2];  // memories   [64,8192,64]
    const float* tmpr = (const float*)d_in[3];  // tmpr       [64,1]
    const int*   mask = (const int*)d_in[4];    // mask       [64,8192]

    float* out   = (float*)d_out;
    float* out_o = out;                                   // outputs  [64,64]
    float* out_w = out + U_UNITS * D_DIM;                 // weights  [64,8192]
    float* out_m = out_w + (size_t)U_UNITS * M_SLOTS;     // memories [64,8192,64]

    float* ws    = (float*)d_ws;
    float* pmax  = ws;                                // U*SCH
    float* psum  = pmax + U_UNITS * SCH;              // U*SCH
    float* alpha = psum + U_UNITS * SCH;              // U*SCH
    float* pout  = alpha + U_UNITS * SCH;             // U*SCH*D

    fused_kernel<<<U_UNITS * SCH, BLK, 0, stream>>>(
        att, atts, tmpr, mask, mem, out_w, out_m, pmax, psum, pout);
    combine_out_kernel<<<U_UNITS, D_DIM, 0, stream>>>(pmax, psum, pout, alpha, out_o);
    wfix_kernel<<<(U_UNITS * M_SLOTS / 4) / BLK, BLK, 0, stream>>>(alpha, out_w);
}